// Round 2
// baseline (1608.339 us; speedup 1.0000x reference)
//
#include <hip/hip_runtime.h>
#include <cstddef>

#define T_STEPS 512
#define BATCH   64
#define EDIM    512
#define HDIM    512
#define ODIM    512

#define HPAD    520                // hsm row stride (bf16): 16B-aligned, 2-way banks (free)
#define W_ELEMS (32 * 4 * 64 * 8)  // W kt 0..3: 131072 B
#define H_ELEMS (16 * HPAD)        // 16640 B
#define SMEM_BYTES ((W_ELEMS + H_ELEMS) * 2)   // 147712

typedef __bf16 bf16;
typedef __bf16 bf16x4 __attribute__((ext_vector_type(4)));
typedef __bf16 bf16x8 __attribute__((ext_vector_type(8)));
typedef float  f32x4  __attribute__((ext_vector_type(4)));

// ---------------------------------------------------------------------------
// MFMA GEMM (round-5 proven): C[r,n] = sum_k X[r,k] * W[n, kw0+k] + bias[n]
// 128x128 tile, BK=32, 4 waves. Frag layouts proven r2/r4/r5.
// REMAP (proven round-1): store C with rows remapped  b*T+t -> t*B+b
// ([B,T,*] -> [T,B,*]) so the scan reads one contiguous [B,H] slab per step.
// ---------------------------------------------------------------------------
template <typename XT, bool REMAP>
__global__ __launch_bounds__(256) void gemm_mfma_kernel(
    const XT* __restrict__ X, int ldx,
    const float* __restrict__ W, int ldw, int kw0,
    const float* __restrict__ bias,
    float* __restrict__ C, int ldc, int K)
{
  __shared__ __align__(16) bf16 Asm[8 * 64 * 8];
  __shared__ __align__(16) bf16 Bsm[8 * 64 * 8];

  const int tid  = threadIdx.x;
  const int row0 = blockIdx.x * 128;
  const int col0 = blockIdx.y * 128;
  const int w    = tid >> 6, lane = tid & 63;
  const int q    = lane >> 4, nl = lane & 15;
  const int wm   = w >> 1, wn = w & 1;

  f32x4 acc[4][4] = {};

  for (int k0 = 0; k0 < K; k0 += 32) {
#pragma unroll
    for (int rep = 0; rep < 2; ++rep) {
      int idx = tid + rep * 256;
      int mt = idx >> 6, l2 = idx & 63;
      const XT* src = X + (size_t)(row0 + mt * 16 + (l2 & 15)) * ldx
                        + k0 + (l2 >> 4) * 8;
      bf16x8 v;
#pragma unroll
      for (int u = 0; u < 8; ++u) v[u] = (bf16)(float)src[u];
      *(bf16x8*)&Asm[(size_t)idx * 8] = v;
    }
#pragma unroll
    for (int rep = 0; rep < 2; ++rep) {
      int idx = tid + rep * 256;
      int nt = idx >> 6, l2 = idx & 63;
      const float* src = W + (size_t)(col0 + nt * 16 + (l2 & 15)) * ldw
                           + kw0 + k0 + (l2 >> 4) * 8;
      bf16x8 v;
#pragma unroll
      for (int u = 0; u < 8; ++u) v[u] = (bf16)src[u];
      *(bf16x8*)&Bsm[(size_t)idx * 8] = v;
    }
    __syncthreads();

    bf16x8 a[4], b[4];
#pragma unroll
    for (int i = 0; i < 4; ++i)
      a[i] = *(bf16x8*)&Asm[(size_t)((wm * 4 + i) * 64 + lane) * 8];
#pragma unroll
    for (int j = 0; j < 4; ++j)
      b[j] = *(bf16x8*)&Bsm[(size_t)((wn * 4 + j) * 64 + lane) * 8];
#pragma unroll
    for (int i = 0; i < 4; ++i)
#pragma unroll
      for (int j = 0; j < 4; ++j)
        acc[i][j] = __builtin_amdgcn_mfma_f32_16x16x32_bf16(a[i], b[j], acc[i][j], 0, 0, 0);
    __syncthreads();
  }

#pragma unroll
  for (int i = 0; i < 4; ++i)
#pragma unroll
    for (int j = 0; j < 4; ++j) {
      int colg = col0 + wn * 64 + j * 16 + nl;
#pragma unroll
      for (int r = 0; r < 4; ++r) {
        size_t rowg = (size_t)(row0 + wm * 64 + i * 16 + q * 4 + r);
        size_t crow = REMAP ? (((rowg & (T_STEPS - 1)) << 6) | (rowg >> 9)) : rowg;
        C[crow * ldc + colg] = acc[i][j][r] + bias[colg];
      }
    }
}

// ---------------------------------------------------------------------------
// BIG scan, swap-ported: 4 workgroups x 512 threads (8 waves), one per
// cluster of 16 batch rows; ALL 512 cols -> recurrence closes with
// __syncthreads only (round-1 lesson: cross-block per-step exchange is fatal).
// Dynamic LDS 147,712 B: W1h kt 0..3 (128 KB) + hsm (16.6 KB).
// W1h kt 4..15 in 192 VGPRs/lane. All frag layouts proven r0/r1:
//   W (A-op):  lane (q,nl) holds W1[n_tile+nl][k = kt*32 + q*8 + u]
//   h (B-op):  lane (q,nl) holds h[row nl][k = kt*32 + q*8 + u]  (same bytes)
//   D:         lane (q,nl) holds out[col n_tile + q*4 + r][row nl]
// Swap benefits vs round-0:
//   - A prefetch: 4x f32x4 (t-major A from REMAP GEMM) instead of 16 scalars
//   - h_t write:  4x ds_write_b64 instead of 16 scalar ds_write_b16
//   - h_t kept in regs (hprev) -> Hbf store issued at TOP of next step,
//     drains at the post-MFMA barrier ~2500 cyc later (hidden); the old
//     stream-out phase (hsm re-read + store) is gone entirely.
// ---------------------------------------------------------------------------
__global__ __launch_bounds__(512, 2) void scan_big_kernel(
    const float* __restrict__ A,     // [T, B, H] fp32 (t-major, from REMAP GEMM)
    const float* __restrict__ W1,    // [H, E+H] fp32
    bf16* __restrict__ Hbf)          // [B, T, H] bf16
{
  extern __shared__ __align__(16) bf16 smem[];
  bf16* Wlds = smem;                 // [tg(32)][kt(4)][lane(64)][8]
  bf16* hsm  = smem + W_ELEMS;       // [16][HPAD]

  const int tid  = threadIdx.x;
  const int c    = blockIdx.x;
  const int w    = tid >> 6, lane = tid & 63;
  const int q    = lane >> 4, nl = lane & 15;
  const int rb0  = c * 16;

  // ---- one-time: W kt 0..3, all 32 n-tiles -> LDS ------------------------
  for (int idx = tid; idx < 32 * 4 * 64; idx += 512) {
    int l  = idx & 63;
    int kt = (idx >> 6) & 3;
    int tg = idx >> 8;
    int n  = tg * 16 + (l & 15);
    int k  = kt * 32 + (l >> 4) * 8;
    const float* src = W1 + (size_t)n * (EDIM + HDIM) + EDIM + k;
    bf16x8 v;
#pragma unroll
    for (int u = 0; u < 8; ++u) v[u] = (bf16)src[u];
    *(bf16x8*)&Wlds[(size_t)idx * 8] = v;
  }

  // ---- one-time: W kt 4..15 for this wave's 4 tiles -> 192 VGPRs ---------
  bf16x8 Wreg[4][12];
#pragma unroll
  for (int i = 0; i < 4; ++i) {
    int n = w * 64 + i * 16 + nl;
    const float* wrow = W1 + (size_t)n * (EDIM + HDIM) + EDIM;
#pragma unroll
    for (int kt2 = 0; kt2 < 12; ++kt2) {
      const float* src = wrow + (kt2 + 4) * 32 + q * 8;
      bf16x8 v;
#pragma unroll
      for (int u = 0; u < 8; ++u) v[u] = (bf16)src[u];
      Wreg[i][kt2] = v;
    }
  }
  __syncthreads();

  // ---- prefetch A_0 (4x f32x4; t-major A) --------------------------------
  f32x4 An[4];
  {
    const float* ap = A + (size_t)(rb0 + nl) * HDIM + w * 64 + q * 4;
    An[0] = *(const f32x4*)(ap);
    An[1] = *(const f32x4*)(ap + 16);
    An[2] = *(const f32x4*)(ap + 32);
    An[3] = *(const f32x4*)(ap + 48);
  }

  f32x4  acc[4];
  bf16x4 hprev[4];

  for (int t = 0; t < T_STEPS; ++t) {
    // ---- deferred store of h_{t-1} from regs (drains at post-MFMA bar) ---
    if (t > 0) {
      bf16* dst = Hbf + ((size_t)(rb0 + nl) * T_STEPS + (t - 1)) * HDIM
                  + w * 64 + q * 4;
      *(bf16x4*)(dst)      = hprev[0];
      *(bf16x4*)(dst + 16) = hprev[1];
      *(bf16x4*)(dst + 32) = hprev[2];
      *(bf16x4*)(dst + 48) = hprev[3];
    }

    // ---- acc init from prefetched A_t; issue A_{t+1} prefetch ------------
#pragma unroll
    for (int i = 0; i < 4; ++i) acc[i] = An[i];
    {
      int tn = (t + 1 < T_STEPS) ? t + 1 : 0;
      const float* ap = A + ((size_t)tn * BATCH + rb0 + nl) * HDIM + w * 64 + q * 4;
      An[0] = *(const f32x4*)(ap);
      An[1] = *(const f32x4*)(ap + 16);
      An[2] = *(const f32x4*)(ap + 32);
      An[3] = *(const f32x4*)(ap + 48);
    }

    // ---- h_{t-1} @ W1h^T over full K=512 (operand-swapped MFMA) ----------
    if (t > 0) {
#pragma unroll
      for (int kt = 0; kt < 16; ++kt) {
        bf16x8 af = *(bf16x8*)&hsm[nl * HPAD + kt * 32 + q * 8];
        if (kt < 4) {
#pragma unroll
          for (int i = 0; i < 4; ++i) {
            bf16x8 wb = *(bf16x8*)&Wlds[(size_t)(((w * 4 + i) * 4 + kt) * 64 + lane) * 8];
            acc[i] = __builtin_amdgcn_mfma_f32_16x16x32_bf16(wb, af, acc[i], 0, 0, 0);
          }
        } else {
#pragma unroll
          for (int i = 0; i < 4; ++i)
            acc[i] = __builtin_amdgcn_mfma_f32_16x16x32_bf16(Wreg[i][kt - 4], af, acc[i], 0, 0, 0);
        }
      }
    }

    __syncthreads();   // all hsm reads of h_{t-1} done; top-of-step vmem drained

    // ---- relu + packed write h_t to hsm; keep in regs for deferred store -
#pragma unroll
    for (int i = 0; i < 4; ++i) {
      bf16x4 hv;
#pragma unroll
      for (int r = 0; r < 4; ++r) {
        float v = acc[i][r] > 0.0f ? acc[i][r] : 0.0f;
        hv[r] = (bf16)v;
      }
      *(bf16x4*)&hsm[nl * HPAD + w * 64 + i * 16 + q * 4] = hv;
      hprev[i] = hv;
    }

    __syncthreads();   // h_t visible to all waves (lgkm-only drain)
  }

  // ---- epilogue: store h_{T-1} -------------------------------------------
  {
    bf16* dst = Hbf + ((size_t)(rb0 + nl) * T_STEPS + (T_STEPS - 1)) * HDIM
                + w * 64 + q * 4;
    *(bf16x4*)(dst)      = hprev[0];
    *(bf16x4*)(dst + 16) = hprev[1];
    *(bf16x4*)(dst + 32) = hprev[2];
    *(bf16x4*)(dst + 48) = hprev[3];
  }
}

// ---------------------------------------------------------------------------
__global__ __launch_bounds__(256) void copy_hfinal_kernel(
    const bf16* __restrict__ Hbf, float* __restrict__ out)
{
  int i = blockIdx.x * blockDim.x + threadIdx.x;
  int b = i / HDIM, n = i % HDIM;
  out[i] = (float)Hbf[((size_t)b * T_STEPS + (T_STEPS - 1)) * HDIM + n];
}

extern "C" void kernel_launch(void* const* d_in, const int* in_sizes, int n_in,
                              void* d_out, int out_size, void* d_ws, size_t ws_size,
                              hipStream_t stream) {
  const float* x  = (const float*)d_in[0];
  const float* W1 = (const float*)d_in[1];
  const float* b1 = (const float*)d_in[2];
  const float* W2 = (const float*)d_in[3];
  const float* b2 = (const float*)d_in[4];

  float* out = (float*)d_out;
  float* A   = out;   // fp32 x-projection staged in d_out ([T,B,H] order);
                      // consumed by the scan before GEMM3 overwrites it

  bf16* Hbf  = (bf16*)d_ws;   // 32 MB

  // 1) A = X @ W1[:, :E]^T + b1  (bf16 MFMA, fp32 out, rows remapped to [T,B])
  {
    dim3 grid(BATCH * T_STEPS / 128, HDIM / 128);
    gemm_mfma_kernel<float, true><<<grid, 256, 0, stream>>>(
        x, EDIM, W1, EDIM + HDIM, 0, b1, A, HDIM, EDIM);
  }

  // 2) scan: 147.7 KB dynamic LDS (attribute opt-in proven on this stack r0)
  hipFuncSetAttribute(
      reinterpret_cast<const void*>(scan_big_kernel),
      hipFuncAttributeMaxDynamicSharedMemorySize, SMEM_BYTES);
  scan_big_kernel<<<4, 512, SMEM_BYTES, stream>>>(A, W1, Hbf);

  // 3) outs = Hbf @ W2^T + b2 (overwrites the A staging area)
  {
    dim3 grid(BATCH * T_STEPS / 128, ODIM / 128);
    gemm_mfma_kernel<bf16, false><<<grid, 256, 0, stream>>>(
        Hbf, HDIM, W2, HDIM, 0, b2, out, ODIM, HDIM);
  }

  // 4) h_final tail
  copy_hfinal_kernel<<<(BATCH * HDIM) / 256, 256, 0, stream>>>(
      Hbf, out + (size_t)BATCH * T_STEPS * ODIM);
}

// Round 3
// 1421.634 us; speedup vs baseline: 1.1313x; 1.1313x over previous
//
#include <hip/hip_runtime.h>
#include <cstddef>

#define T_STEPS 512
#define BATCH   64
#define EDIM    512
#define HDIM    512
#define ODIM    512

#define W_ELEMS  (32 * 4 * 64 * 8)  // W kt 0..3: 65536 elems = 131072 B
#define HB_ELEMS (16 * 512)         // one h buffer: 8192 elems = 16384 B

typedef __bf16 bf16;
typedef __bf16 bf16x4 __attribute__((ext_vector_type(4)));
typedef __bf16 bf16x8 __attribute__((ext_vector_type(8)));
typedef float  f32x4  __attribute__((ext_vector_type(4)));

// LDS-only barrier: does NOT drain vmcnt, so in-flight global loads/stores
// (A prefetch, Hbf stores) ride across it. rule-18 fence: sched_barrier after.
__device__ __forceinline__ void barrier_lds() {
  asm volatile("s_waitcnt lgkmcnt(0)\n\ts_barrier" ::: "memory");
  __builtin_amdgcn_sched_barrier(0);
}

// ---------------------------------------------------------------------------
// MFMA GEMM (proven r0-r2): C[r,n] = sum_k X[r,k] * W[n, kw0+k] + bias[n]
// 128x128 tile, BK=32, 4 waves. REMAP (proven r1/r2): rows b*T+t -> t*B+b.
// ---------------------------------------------------------------------------
template <typename XT, bool REMAP>
__global__ __launch_bounds__(256) void gemm_mfma_kernel(
    const XT* __restrict__ X, int ldx,
    const float* __restrict__ W, int ldw, int kw0,
    const float* __restrict__ bias,
    float* __restrict__ C, int ldc, int K)
{
  __shared__ __align__(16) bf16 Asm[8 * 64 * 8];
  __shared__ __align__(16) bf16 Bsm[8 * 64 * 8];

  const int tid  = threadIdx.x;
  const int row0 = blockIdx.x * 128;
  const int col0 = blockIdx.y * 128;
  const int w    = tid >> 6, lane = tid & 63;
  const int q    = lane >> 4, nl = lane & 15;
  const int wm   = w >> 1, wn = w & 1;

  f32x4 acc[4][4] = {};

  for (int k0 = 0; k0 < K; k0 += 32) {
#pragma unroll
    for (int rep = 0; rep < 2; ++rep) {
      int idx = tid + rep * 256;
      int mt = idx >> 6, l2 = idx & 63;
      const XT* src = X + (size_t)(row0 + mt * 16 + (l2 & 15)) * ldx
                        + k0 + (l2 >> 4) * 8;
      bf16x8 v;
#pragma unroll
      for (int u = 0; u < 8; ++u) v[u] = (bf16)(float)src[u];
      *(bf16x8*)&Asm[(size_t)idx * 8] = v;
    }
#pragma unroll
    for (int rep = 0; rep < 2; ++rep) {
      int idx = tid + rep * 256;
      int nt = idx >> 6, l2 = idx & 63;
      const float* src = W + (size_t)(col0 + nt * 16 + (l2 & 15)) * ldw
                           + kw0 + k0 + (l2 >> 4) * 8;
      bf16x8 v;
#pragma unroll
      for (int u = 0; u < 8; ++u) v[u] = (bf16)src[u];
      *(bf16x8*)&Bsm[(size_t)idx * 8] = v;
    }
    __syncthreads();

    bf16x8 a[4], b[4];
#pragma unroll
    for (int i = 0; i < 4; ++i)
      a[i] = *(bf16x8*)&Asm[(size_t)((wm * 4 + i) * 64 + lane) * 8];
#pragma unroll
    for (int j = 0; j < 4; ++j)
      b[j] = *(bf16x8*)&Bsm[(size_t)((wn * 4 + j) * 64 + lane) * 8];
#pragma unroll
    for (int i = 0; i < 4; ++i)
#pragma unroll
      for (int j = 0; j < 4; ++j)
        acc[i][j] = __builtin_amdgcn_mfma_f32_16x16x32_bf16(a[i], b[j], acc[i][j], 0, 0, 0);
    __syncthreads();
  }

#pragma unroll
  for (int i = 0; i < 4; ++i)
#pragma unroll
    for (int j = 0; j < 4; ++j) {
      int colg = col0 + wn * 64 + j * 16 + nl;
#pragma unroll
      for (int r = 0; r < 4; ++r) {
        size_t rowg = (size_t)(row0 + wm * 64 + i * 16 + q * 4 + r);
        size_t crow = REMAP ? (((rowg & (T_STEPS - 1)) << 6) | (rowg >> 9)) : rowg;
        C[crow * ldc + colg] = acc[i][j][r] + bias[colg];
      }
    }
}

// ---------------------------------------------------------------------------
// Scan, round-3: 4 WGs x 512 threads (8 waves), recurrence closes in-block.
// Changes vs round-0 (1152 us proven):
//   - operand-swapped MFMA (r2-proven layouts): D gives lane (q,nl)
//     h[row nl][cols n0+i*16+q*4 .. +3] -> writer AND reader key on row nl
//   - XOR swizzle (elem ^= (nl&7)<<3) instead of HPAD padding: af-read
//     start-bank = 4*(q ^ (nl&7)) -> 2 lanes/bank (free)
//   - double-buffered h (DBUF=1, 160 KiB LDS exactly) -> ONE barrier/step
//   - LDS-only barrier (no vmcnt drain); h_t stored to Hbf directly from
//     regs in the write phase; stores retire lazily across later steps
//   - NO new cross-step register liveness (r2 lesson: 256-reg cliff)
// W1h kt 0..3 in LDS (128 KB), kt 4..15 in 192 regs/lane (r0 split).
// ---------------------------------------------------------------------------
template <int DBUF>
__global__ __launch_bounds__(512, 2) void scan_kernel(
    const float* __restrict__ A,     // [T, B, H] fp32 (t-major, REMAP GEMM)
    const float* __restrict__ W1,    // [H, E+H] fp32
    bf16* __restrict__ Hbf)          // [B, T, H] bf16
{
  extern __shared__ __align__(16) bf16 smem[];
  bf16* Wlds = smem;                       // [tg(32)][kt(4)][lane(64)][8]
  bf16* hb0  = smem + W_ELEMS;             // [16][512] swizzled
  bf16* hb1  = DBUF ? (hb0 + HB_ELEMS) : hb0;

  const int tid  = threadIdx.x;
  const int c    = blockIdx.x;
  const int w    = tid >> 6, lane = tid & 63;
  const int q    = lane >> 4, nl = lane & 15;
  const int rb0  = c * 16;
  const int n0   = w * 64;
  const int sw   = (nl & 7) << 3;          // elem-granularity row swizzle

  // ---- one-time: W kt 0..3, all 32 n-tiles -> LDS ------------------------
  for (int idx = tid; idx < 32 * 4 * 64; idx += 512) {
    int l  = idx & 63;
    int kt = (idx >> 6) & 3;
    int tg = idx >> 8;
    int n  = tg * 16 + (l & 15);
    int k  = kt * 32 + (l >> 4) * 8;
    const float* src = W1 + (size_t)n * (EDIM + HDIM) + EDIM + k;
    bf16x8 v;
#pragma unroll
    for (int u = 0; u < 8; ++u) v[u] = (bf16)src[u];
    *(bf16x8*)&Wlds[(size_t)idx * 8] = v;
  }

  // ---- one-time: W kt 4..15 for this wave's 4 tiles -> 192 VGPRs ---------
  bf16x8 Wreg[4][12];
#pragma unroll
  for (int i = 0; i < 4; ++i) {
    int n = n0 + i * 16 + nl;
    const float* wrow = W1 + (size_t)n * (EDIM + HDIM) + EDIM;
#pragma unroll
    for (int kt2 = 0; kt2 < 12; ++kt2) {
      const float* src = wrow + (kt2 + 4) * 32 + q * 8;
      bf16x8 v;
#pragma unroll
      for (int u = 0; u < 8; ++u) v[u] = (bf16)src[u];
      Wreg[i][kt2] = v;
    }
  }
  __syncthreads();

  // ---- prefetch A_0 (4x f32x4; t-major A; r2-proven mapping) -------------
  f32x4 An[4];
  {
    const float* ap = A + (size_t)(rb0 + nl) * HDIM + n0 + q * 4;
    An[0] = *(const f32x4*)(ap);
    An[1] = *(const f32x4*)(ap + 16);
    An[2] = *(const f32x4*)(ap + 32);
    An[3] = *(const f32x4*)(ap + 48);
  }

  f32x4 acc[4];

  for (int t = 0; t < T_STEPS; ++t) {
    // h_{t-1} lives in hr; h_t goes to hw (parity proven: hw(t-1)==hr(t))
    bf16* hr = (t & 1) ? hb1 : hb0;
    bf16* hw = (t & 1) ? hb0 : hb1;

    // ---- acc init from prefetched A_t; issue A_{t+1} prefetch ------------
#pragma unroll
    for (int i = 0; i < 4; ++i) acc[i] = An[i];
    {
      int tn = (t + 1 < T_STEPS) ? t + 1 : 0;
      const float* ap = A + ((size_t)tn * BATCH + rb0 + nl) * HDIM + n0 + q * 4;
      An[0] = *(const f32x4*)(ap);
      An[1] = *(const f32x4*)(ap + 16);
      An[2] = *(const f32x4*)(ap + 32);
      An[3] = *(const f32x4*)(ap + 48);
    }

    // ---- h_{t-1} @ W1h^T over K=512 (operand-swapped MFMA, r2-proven) ----
    if (t > 0) {
#pragma unroll
      for (int kt = 0; kt < 16; ++kt) {
        bf16x8 af = *(bf16x8*)&hr[nl * 512 + ((kt * 32 + q * 8) ^ sw)];
        if (kt < 4) {
#pragma unroll
          for (int i = 0; i < 4; ++i) {
            bf16x8 wb = *(bf16x8*)&Wlds[(size_t)(((w * 4 + i) * 4 + kt) * 64 + lane) * 8];
            acc[i] = __builtin_amdgcn_mfma_f32_16x16x32_bf16(wb, af, acc[i], 0, 0, 0);
          }
        } else {
#pragma unroll
          for (int i = 0; i < 4; ++i)
            acc[i] = __builtin_amdgcn_mfma_f32_16x16x32_bf16(Wreg[i][kt - 4], af, acc[i], 0, 0, 0);
        }
      }
    }

    if (!DBUF) barrier_lds();   // single-buffer WAR: reads done before overwrite

    // ---- relu; write h_t to hw (swizzled) + Hbf directly from regs -------
#pragma unroll
    for (int i = 0; i < 4; ++i) {
      bf16x4 hv;
#pragma unroll
      for (int r = 0; r < 4; ++r) {
        float v = acc[i][r] > 0.0f ? acc[i][r] : 0.0f;
        hv[r] = (bf16)v;
      }
      *(bf16x4*)&hw[nl * 512 + ((n0 + i * 16 + q * 4) ^ sw)] = hv;
      *(bf16x4*)(Hbf + ((size_t)(rb0 + nl) * T_STEPS + t) * HDIM
                 + n0 + i * 16 + q * 4) = hv;
    }

    barrier_lds();   // h_t visible; also orders this step's hr reads vs
                     // next step's hw(==hr) writes in the DBUF case
  }
}

// ---------------------------------------------------------------------------
__global__ __launch_bounds__(256) void copy_hfinal_kernel(
    const bf16* __restrict__ Hbf, float* __restrict__ out)
{
  int i = blockIdx.x * blockDim.x + threadIdx.x;
  int b = i / HDIM, n = i % HDIM;
  out[i] = (float)Hbf[((size_t)b * T_STEPS + (T_STEPS - 1)) * HDIM + n];
}

extern "C" void kernel_launch(void* const* d_in, const int* in_sizes, int n_in,
                              void* d_out, int out_size, void* d_ws, size_t ws_size,
                              hipStream_t stream) {
  const float* x  = (const float*)d_in[0];
  const float* W1 = (const float*)d_in[1];
  const float* b1 = (const float*)d_in[2];
  const float* W2 = (const float*)d_in[3];
  const float* b2 = (const float*)d_in[4];

  float* out = (float*)d_out;
  float* A   = out;   // fp32 x-projection staged in d_out ([T,B,H] order);
                      // consumed by the scan before GEMM3 overwrites it

  bf16* Hbf  = (bf16*)d_ws;   // 32 MB

  // 1) A = X @ W1[:, :E]^T + b1  (bf16 MFMA, fp32 out, rows remapped to [T,B])
  {
    dim3 grid(BATCH * T_STEPS / 128, HDIM / 128);
    gemm_mfma_kernel<float, true><<<grid, 256, 0, stream>>>(
        x, EDIM, W1, EDIM + HDIM, 0, b1, A, HDIM, EDIM);
  }

  // 2) scan. DBUF needs 163,840 B dynamic LDS (exactly 160 KiB); if the
  // attribute isn't granted, fall back to the single-buffer 2-barrier
  // variant (147,456 B, proven-size territory from r0's 147,712).
  {
    int smem_dbuf = (W_ELEMS + 2 * HB_ELEMS) * 2;   // 163840
    int smem_sbuf = (W_ELEMS + 1 * HB_ELEMS) * 2;   // 147456
    hipError_t e = hipFuncSetAttribute(
        reinterpret_cast<const void*>(scan_kernel<1>),
        hipFuncAttributeMaxDynamicSharedMemorySize, smem_dbuf);
    if (e == hipSuccess) {
      scan_kernel<1><<<4, 512, smem_dbuf, stream>>>(A, W1, Hbf);
    } else {
      hipFuncSetAttribute(
          reinterpret_cast<const void*>(scan_kernel<0>),
          hipFuncAttributeMaxDynamicSharedMemorySize, smem_sbuf);
      scan_kernel<0><<<4, 512, smem_sbuf, stream>>>(A, W1, Hbf);
    }
  }

  // 3) outs = Hbf @ W2^T + b2 (overwrites the A staging area)
  {
    dim3 grid(BATCH * T_STEPS / 128, ODIM / 128);
    gemm_mfma_kernel<bf16, false><<<grid, 256, 0, stream>>>(
        Hbf, HDIM, W2, HDIM, 0, b2, out, ODIM, HDIM);
  }

  // 4) h_final tail
  copy_hfinal_kernel<<<(BATCH * HDIM) / 256, 256, 0, stream>>>(
      Hbf, out + (size_t)BATCH * T_STEPS * ODIM);
}